// Round 4
// baseline (392.268 us; speedup 1.0000x reference)
//
#include <hip/hip_runtime.h>
#include <hip/hip_bf16.h>

typedef __hip_bfloat16 bf16;
typedef unsigned char u8;
typedef __attribute__((ext_vector_type(4))) float f32x4;
typedef __attribute__((ext_vector_type(8))) int i32x8;
typedef __attribute__((ext_vector_type(4))) unsigned int u32x4;

struct L4 { long a, b, c, d; };
struct U2 { u32x4 x, y; };

// async global->LDS 16B copy; LDS dst must be wave-uniform base + lane*16
typedef __attribute__((address_space(3))) unsigned int lds_uint;
typedef __attribute__((address_space(1))) const unsigned int g_uint;
__device__ inline void gload_lds16(const void* g, void* l) {
    __builtin_amdgcn_global_load_lds((g_uint*)g, (lds_uint*)l, 16, 0, 0);
}

__device__ inline void block_reduce_atomic(float v, float* dst) {
    #pragma unroll
    for (int o = 32; o > 0; o >>= 1) v += __shfl_down(v, o, 64);
    __shared__ float ws[8];
    const int lane = threadIdx.x & 63;
    const int wid  = threadIdx.x >> 6;
    if (lane == 0) ws[wid] = v;
    __syncthreads();
    if (threadIdx.x == 0) {
        float s = 0.f;
        const int nw = (blockDim.x + 63) >> 6;
        for (int i = 0; i < nw; ++i) s += ws[i];
        atomicAdd(dst, s);
    }
}

// ---------------------------------------------------------------------------
// prep+loss+conv1 merged (accs/zbuf zeroed by hipMemsetAsync before this).
// blocks [0,3744): weight repack to MX layout; [3744,6216): ssim + mse;
// [6216,6216+c1n): conv1 for all 16 images (nb==8 fast path).
// wt layout per 32ch phase p: [t0..7][q(16ch)][CO][16B] then tap8 [q][CO][16B]
// ---------------------------------------------------------------------------
__global__ void prep_loss_kernel(
    const float* __restrict__ w2, u8* __restrict__ wb2,
    const float* __restrict__ w3, u8* __restrict__ wb3,
    const float* __restrict__ w4, u8* __restrict__ wb4,
    const float* __restrict__ x, const float* __restrict__ y,
    float* __restrict__ accs,
    const float* __restrict__ w1, const float* __restrict__ b1,
    u8* __restrict__ aout) {
    const int blk = blockIdx.x;
    if (blk >= 6216) {
        // conv1: CIN=1, CO=64, fp32 NCHW -> fp8 planar NC8HW8, relu. 16 imgs.
        const int lb2 = blk - 6216;
        const int img = lb2 >> 8;
        const float* in = (img < 8) ? (x + (size_t)img * 65536)
                                    : (y + (size_t)(img - 8) * 65536);
        const int px = ((lb2 & 255) << 8) + threadIdx.x;
        const int yy = px >> 8, xx = px & 255;
        float p[9];
        #pragma unroll
        for (int dy = 0; dy < 3; ++dy)
            #pragma unroll
            for (int dx = 0; dx < 3; ++dx) {
                int gy = yy + dy - 1, gx = xx + dx - 1;
                float v = 0.f;
                if ((unsigned)gy < 256u && (unsigned)gx < 256u)
                    v = in[(size_t)gy * 256 + gx];
                p[dy * 3 + dx] = v;
            }
        #pragma unroll
        for (int g = 0; g < 8; ++g) {
            float v[8];
            #pragma unroll
            for (int c = 0; c < 8; ++c) {
                int co = g * 8 + c;
                float a = b1[co];
                #pragma unroll
                for (int k = 0; k < 9; ++k) a += w1[co * 9 + k] * p[k];
                v[c] = fmaxf(a, 0.f);
            }
            uint2 o;
            int r;
            r = __builtin_amdgcn_cvt_pk_fp8_f32(v[0], v[1], 0, false);
            o.x = __builtin_amdgcn_cvt_pk_fp8_f32(v[2], v[3], r, true);
            r = __builtin_amdgcn_cvt_pk_fp8_f32(v[4], v[5], 0, false);
            o.y = __builtin_amdgcn_cvt_pk_fp8_f32(v[6], v[7], r, true);
            *(uint2*)(aout + (((size_t)img * 8 + g) * 65536 + px) * 8) = o;
        }
        return;
    }
    if (blk < 3744) {
        const float* w; u8* wb; int CIN, CO, idx;
        if (blk < 288)       { w = w2; wb = wb2; CIN = 64;  CO = 128; idx = blk * 256 + threadIdx.x; }
        else if (blk < 1440) { w = w3; wb = wb3; CIN = 128; CO = 256; idx = (blk - 288) * 256 + threadIdx.x; }
        else                 { w = w4; wb = wb4; CIN = 256; CO = 256; idx = (blk - 1440) * 256 + threadIdx.x; }
        int n = CO * 9 * CIN;
        if (idx >= n) return;
        int t = idx % 9;
        int rest = idx / 9;
        int ci = rest % CIN;
        int co = rest / CIN;
        float v = w[idx];            // w flat = ((co*CIN+ci)*9 + t)
        int p = ci >> 5, c32 = ci & 31;
        size_t off = (size_t)p * 288 * CO;
        if (t < 8) off += (((size_t)t * 2 + (c32 >> 4)) * CO + co) * 16 + (c32 & 15);
        else       off += 256 * (size_t)CO + (((size_t)(c32 >> 4)) * CO + co) * 16 + (c32 & 15);
        int r = __builtin_amdgcn_cvt_pk_fp8_f32(v, v, 0, false);
        wb[off] = (u8)(r & 0xff);
        return;
    }
    const int lb = blk - 3744;
    float val = 0.f;
    float* dst;
    if (lb < 1960) {
        dst = accs + 1;
        const int b = lb / 245;
        const int t = (lb - b * 245) * 256 + threadIdx.x;
        if (t < 250 * 250) {
            const int i = t / 250, j = t - (t / 250) * 250;
            const float* xp = x + (size_t)b * 65536;
            const float* yp = y + (size_t)b * 65536;
            float sx = 0.f, sy = 0.f, sxx = 0.f, syy = 0.f, sxy = 0.f;
            #pragma unroll
            for (int dy = 0; dy < 7; ++dy) {
                const float* xr = xp + (size_t)(i + dy) * 256 + j;
                const float* yr = yp + (size_t)(i + dy) * 256 + j;
                #pragma unroll
                for (int dx = 0; dx < 7; ++dx) {
                    float a = xr[dx], c = yr[dx];
                    sx += a; sy += c;
                    sxx += a * a; syy += c * c; sxy += a * c;
                }
            }
            const float inv = 1.f / 49.f;
            const float cn  = 49.f / 48.f;
            float ux = sx * inv, uy = sy * inv;
            float vx  = cn * (sxx * inv - ux * ux);
            float vy  = cn * (syy * inv - uy * uy);
            float vxy = cn * (sxy * inv - ux * uy);
            const float C1 = 1e-4f, C2 = 9e-4f;
            val = ((2.f * ux * uy + C1) * (2.f * vxy + C2)) /
                  ((ux * ux + uy * uy + C1) * (vx + vy + C2));
        }
    } else {
        dst = accs + 0;
        int i = (lb - 1960) * 256 + threadIdx.x;   // < 131072 float4s
        float4 a = ((const float4*)x)[i];
        float4 b = ((const float4*)y)[i];
        float d0 = a.x - b.x, d1 = a.y - b.y, d2 = a.z - b.z, d3 = a.w - b.w;
        val = d0 * d0 + d1 * d1 + d2 * d2 + d3 * d3;
    }
    block_reduce_atomic(val, dst);
}

__global__ void finalize_kernel(const float* __restrict__ accs, float* __restrict__ out) {
    if (threadIdx.x == 0) {
        float mse    = accs[0] * (1.f / 524288.f);
        float ssim_l = 1.f - accs[1] * (1.f / 500000.f);
        float perc   = accs[2] * (1.f / 33554432.f);
        out[0] = mse + 0.5f * ssim_l + 0.1f * perc;
        out[1] = mse;
        out[2] = ssim_l;
        out[3] = perc;
    }
}

// ---------------------------------------------------------------------------
// conv1 standalone (fallback for nb<8 workspace-constrained path).
// ---------------------------------------------------------------------------
__global__ __launch_bounds__(256) void conv1_kernel(
    const float* __restrict__ sr, const float* __restrict__ hr, int nb, int b0,
    const float* __restrict__ w, const float* __restrict__ bias,
    u8* __restrict__ out) {
    const int H = 256, W = 256;
    const int img = blockIdx.y;
    const float* in = (img < nb) ? (sr + (size_t)(b0 + img) * 65536)
                                 : (hr + (size_t)(b0 + img - nb) * 65536);
    int px = blockIdx.x * 256 + threadIdx.x;
    int y = px >> 8, x = px & 255;
    float p[9];
    #pragma unroll
    for (int dy = 0; dy < 3; ++dy)
        #pragma unroll
        for (int dx = 0; dx < 3; ++dx) {
            int gy = y + dy - 1, gx = x + dx - 1;
            float v = 0.f;
            if ((unsigned)gy < (unsigned)H && (unsigned)gx < (unsigned)W)
                v = in[(size_t)gy * W + gx];
            p[dy * 3 + dx] = v;
        }
    #pragma unroll
    for (int g = 0; g < 8; ++g) {
        float v[8];
        #pragma unroll
        for (int c = 0; c < 8; ++c) {
            int co = g * 8 + c;
            float a = bias[co];
            #pragma unroll
            for (int k = 0; k < 9; ++k) a += w[co * 9 + k] * p[k];
            v[c] = fmaxf(a, 0.f);
        }
        uint2 o;
        int r;
        r = __builtin_amdgcn_cvt_pk_fp8_f32(v[0], v[1], 0, false);
        o.x = __builtin_amdgcn_cvt_pk_fp8_f32(v[2], v[3], r, true);
        r = __builtin_amdgcn_cvt_pk_fp8_f32(v[4], v[5], 0, false);
        o.y = __builtin_amdgcn_cvt_pk_fp8_f32(v[6], v[7], r, true);
        *(uint2*)(out + (((size_t)img * 8 + g) * 65536 + px) * 8) = o;
    }
}

#define BUF_SZ   32768
#define N_ACT_CH 720
#define N_CHUNK  1872
#define WT_BOFF  11520     // 720*16

// ---------------------------------------------------------------------------
// conv2 SINGLE-STAGE: CIN=64, CO=128, H=W=256, fused 2x2 maxpool.
// Entire working set staged ONCE via 15 gload slots; ONE barrier; both 32-ch
// phases computed back-to-back with zero further syncs. 2 blocks/CU.
// Epilogue emits NC16HW16 (conv34_fused input layout).
// ---------------------------------------------------------------------------
__global__ __launch_bounds__(256, 2) void conv2_ss(
    const u8* __restrict__ in, const u8* __restrict__ wb,
    const float* __restrict__ bias, u8* __restrict__ out,
    const float* __restrict__ zbuf) {
    const int H = 256, W = 256, CO = 128;
    const size_t HW = 65536;
    const int tid  = threadIdx.x;
    const int lane = tid & 63;
    const int wn   = tid >> 6;
    const int xl = lane & 15;
    const int kq = lane >> 4;
    const int x0 = blockIdx.x * 16;
    const int y0 = blockIdx.y * 16;
    const int img = blockIdx.z >> 1;
    const int co0 = (blockIdx.z & 1) << 6;

    __shared__ __align__(16) char smem[59904];

    f32x4 acc[4][4];
    #pragma unroll
    for (int m = 0; m < 4; ++m)
        #pragma unroll
        for (int n = 0; n < 4; ++n) acc[m][n] = (f32x4){0.f, 0.f, 0.f, 0.f};

    const u8* inp = in + (size_t)img * 8 * HW * 8;   // 8 planes

    // ---- stage all 3744 chunks once (15 slots; slot14 partial tid<160) ----
    {
        char* d = smem + tid * 16;
        #pragma unroll
        for (int i = 0; i < 15; ++i) {
            int c = tid + i * 256;
            if (c >= 2 * N_CHUNK) break;
            int ph = (c >= N_CHUNK) ? 1 : 0;
            int c2 = c - ph * N_CHUNK;
            const char* src = (const char*)zbuf;
            if (c2 < N_ACT_CH) {
                int g = c2 / 180, r = c2 - g * 180;
                int row = r / 10, pp = r - row * 10;
                int gy = y0 - 1 + row, colb = x0 - 2 + pp * 2;
                if ((unsigned)gy < (unsigned)H && (unsigned)colb < (unsigned)(W - 1))
                    src = (const char*)(inp + (((size_t)(g + ph * 4)) * HW +
                                              (size_t)gy * W + colb) * 8);
            } else {
                int c3 = c2 - N_ACT_CH;
                size_t o;
                if (c3 < 1024) {
                    int gt = c3 >> 6, co = c3 & 63;
                    o = ((size_t)gt * CO + co0 + co) * 16;
                } else {
                    int c4 = c3 - 1024;
                    int q = c4 >> 6, co = c4 & 63;
                    o = 256 * (size_t)CO + ((size_t)q * CO + co0 + co) * 16;
                }
                src = (const char*)(wb + (size_t)ph * 288 * CO + o);
            }
            gload_lds16(src, d + i * 4096);
        }
    }

    int mxo[2];
    #pragma unroll
    for (int g = 0; g < 2; ++g) {
        int t = g * 4 + kq;
        int dy = t / 3, dx = t - dy * 3;
        mxo[g] = (dy * 20 + dx) * 8;
    }
    const int abase = ((wn * 4) * 20 + xl + 1) * 8;
    const int awmx  = WT_BOFF + kq * 2048 + xl * 16;
    const int aw8   = WT_BOFF + 16384 + (kq >> 1) * 1024 + xl * 16 + (kq & 1) * 8;
    const int ab8   = kq * 2880 + abase + (2 * 20 + 2) * 8;

    __syncthreads();   // single drain

    #pragma unroll
    for (int p = 0; p < 2; ++p) {
        const char* base = smem + p * 29952;
        #pragma unroll
        for (int g = 0; g < 2; ++g) {
            i32x8 A[4];
            #pragma unroll
            for (int mt = 0; mt < 4; ++mt) {
                const char* pa = base + awmx + g * 8192 + mt * 256;
                U2 u{*(const u32x4*)pa, *(const u32x4*)(pa + 1024)};
                A[mt] = __builtin_bit_cast(i32x8, u);
            }
            #pragma unroll
            for (int nt = 0; nt < 4; ++nt) {
                const char* pb = base + abase + mxo[g] + nt * 160;
                L4 l{*(const long*)pb, *(const long*)(pb + 2880),
                     *(const long*)(pb + 5760), *(const long*)(pb + 8640)};
                i32x8 B = __builtin_bit_cast(i32x8, l);
                #pragma unroll
                for (int mt = 0; mt < 4; ++mt)
                    acc[mt][nt] = __builtin_amdgcn_mfma_scale_f32_16x16x128_f8f6f4(
                        A[mt], B, acc[mt][nt], 0, 0,
                        0, 0x7F7F7F7F, 0, 0x7F7F7F7F);
            }
        }
        {
            long A8[4], B8[4];
            #pragma unroll
            for (int mt = 0; mt < 4; ++mt)
                A8[mt] = *(const long*)(base + aw8 + mt * 256);
            #pragma unroll
            for (int nt = 0; nt < 4; ++nt)
                B8[nt] = *(const long*)(base + ab8 + nt * 160);
            #pragma unroll
            for (int mt = 0; mt < 4; ++mt)
                #pragma unroll
                for (int nt = 0; nt < 4; ++nt)
                    acc[mt][nt] = __builtin_amdgcn_mfma_f32_16x16x32_fp8_fp8(
                        A8[mt], B8[nt], acc[mt][nt], 0, 0, 0);
        }
    }

    // pool epilogue (C/D: col=xl; row(co in 16) = kq*4+reg) -> NC16HW16
    const int Hp = H >> 1, Wp = W >> 1;
    const size_t HWp = (size_t)Hp * Wp;
    #pragma unroll
    for (int j = 0; j < 2; ++j) {
        const int py = (y0 + wn * 4 + 2 * j) >> 1;
        const int px = (x0 + xl) >> 1;
        #pragma unroll
        for (int mt = 0; mt < 4; ++mt) {
            const int cb = co0 + mt * 16 + kq * 4;
            const f32x4 bv = *(const f32x4*)(bias + cb);
            float v[4];
            #pragma unroll
            for (int r = 0; r < 4; ++r) {
                float a = acc[mt][2 * j][r] + bv[r];
                float b = acc[mt][2 * j + 1][r] + bv[r];
                float m = fmaxf(a, b);
                m = fmaxf(m, __shfl_xor(m, 1));   // fold x pair
                v[r] = fmaxf(m, 0.f);
            }
            if (!(lane & 1)) {
                int w0 = __builtin_amdgcn_cvt_pk_fp8_f32(v[0], v[1], 0, false);
                w0 = __builtin_amdgcn_cvt_pk_fp8_f32(v[2], v[3], w0, true);
                *(int*)(out + (((size_t)img * (CO >> 4) + (cb >> 4)) * HWp +
                               (size_t)py * Wp + px) * 16 + (cb & 15)) = w0;
            }
        }
    }
}

// ---------------------------------------------------------------------------
// conv34_fused: sr+hr computed TOGETHER each 32-ch phase, shared A-fragments.
// u32 workspace-relative offsets (R2-proven, no spill). NPH = CIN/32 phases.
// EPI: 0 = store both imgs NC16HW16 (conv3), 1 = perceptual reduce (conv4).
// R4: hash-based start-skew de-phases the 2 co-resident blocks per CU so one
// wave's ds_read/stage chain hides under the other's MFMA burst (the two
// blocks otherwise start in lockstep and stall together -- R3 slot analysis:
// 8860 cy = 5688 MFMA + 3172 exposed overhead).
// ---------------------------------------------------------------------------
#define C4_ACT  10368      // one image's act bytes per phase (2*18*18*16)
#define C4_WT   20736      // weight region offset (2*C4_ACT)
#define C4_BUF  39168      // per-phase buffer (C4_WT + 18432)
#define C4_NCH  2448       // chunks per phase (1296 act + 1152 wt)

template <int NPH, int EPI, int IMGSH>
__global__ __launch_bounds__(256, 2) void conv34_fused(
    char* __restrict__ wsb,          // workspace base
    unsigned inOff,                  // input base offset in ws (NC16HW16 fp8)
    unsigned wOff,                   // packed weight offset in ws
    unsigned zOff,                   // zbuf offset in ws
    const float* __restrict__ bias,
    unsigned inHrOff,                // hr image region offset from sr region
    unsigned outOff,                 // EPI0: output base offset in ws
    unsigned outHrOff,               // EPI0: hr output region offset
    float* __restrict__ pacc) {      // EPI1: perceptual accumulator
    const int tid  = threadIdx.x;
    const int lane = tid & 63;
    const int wn   = tid >> 6;
    const int xl = lane & 15;
    const int kq = lane >> 4;
    const int x0 = blockIdx.x * 16;
    const int y0 = blockIdx.y * 16;
    const int img = blockIdx.z >> 2;
    const int co0 = (blockIdx.z & 3) << 6;

    // ---- start-skew: de-phase co-resident blocks (0..~8k cy, ~1 slot) ----
    {
        unsigned h = ((unsigned)blockIdx.x * 0x9E3779B1u) ^
                     ((unsigned)blockIdx.y * 0x85EBCA6Bu) ^
                     ((unsigned)blockIdx.z * 0xC2B2AE35u);
        int slp = (int)((h >> 20) & 63);
        #pragma unroll 1
        for (int i = 0; i < slp; ++i) __builtin_amdgcn_s_sleep(2);
    }

    __shared__ __align__(16) char smem[2 * C4_BUF];   // 78336 B

    f32x4 accS[4][4], accH[4][4];
    #pragma unroll
    for (int m = 0; m < 4; ++m)
        #pragma unroll
        for (int n = 0; n < 4; ++n) {
            accS[m][n] = (f32x4){0.f, 0.f, 0.f, 0.f};
            accH[m][n] = (f32x4){0.f, 0.f, 0.f, 0.f};
        }

    const unsigned inoff = inOff + ((unsigned)img << IMGSH);

    // chunk map: [0,648) sr act, [648,1296) hr act, [1296,2448) weights
    //   act: c2 = g2*324 + row*18 + col  (18x18 exact halo, 16-ch chunks)
    //   wt : c3 < 1024 -> [kblk(16)][co(64)]; else tap8 [h(2)][co(64)]
    unsigned off[10];
    #pragma unroll
    for (int i = 0; i < 10; ++i) {
        int c = tid + i * 256;
        off[i] = zOff;                         // zero-halo sentinel
        if (c < 1296) {
            int c2 = (c >= 648) ? c - 648 : c;
            int g2 = c2 / 324, rem = c2 - g2 * 324;
            int row = rem / 18, col = rem - row * 18;
            int gy = y0 - 1 + row, gx = x0 - 1 + col;
            if ((unsigned)gy < 128u && (unsigned)gx < 128u)
                off[i] = inoff + ((c >= 648) ? inHrOff : 0u) +
                         (unsigned)((g2 * 16384 + gy * 128 + gx) * 16);
        } else if (c < C4_NCH) {
            int c3 = c - 1296;
            unsigned o;
            if (c3 < 1024) {
                int kblk = c3 >> 6, co = c3 & 63;
                o = (unsigned)((kblk * 256 + co0 + co) * 16);
            } else {
                int c4 = c3 - 1024;
                int h = c4 >> 6, co = c4 & 63;
                o = 65536u + (unsigned)((h * 256 + co0 + co) * 16);
            }
            off[i] = wOff + o;
        }
    }

    // B addressing: halo row r = wn*4+nt+dy, col = xl+dx; 16-ch chunk = 16B,
    // row stride 288, g2 (16-ch half) stride 5184 -> 2 x b128 per frag.
    int bmx[2];
    #pragma unroll
    for (int g = 0; g < 2; ++g) {
        int t = g * 4 + kq;
        int dy = t / 3, dx = t - dy * 3;
        bmx[g] = (dy * 18 + dx) * 16;
    }
    const int bnt0 = ((wn * 4) * 18 + xl) * 16;   // + nt*288
    const int awmx = C4_WT + kq * 2048 + xl * 16;
    const int aw8  = C4_WT + 16384 + (kq >> 1) * 1024 + xl * 16 + (kq & 1) * 8;
    const int ab8  = ((wn * 4 + 2) * 18 + xl + 2) * 16 +
                     (kq >> 1) * 5184 + (kq & 1) * 8;     // + nt*288

    // advance per phase: act +524288 (2 planes) unless sentinel; wt +73728
#define C4_STAGE(DB) do {                                                   \
        char* d_ = (DB) + tid * 16;                                         \
        _Pragma("unroll")                                                   \
        for (int i_ = 0; i_ < 10; ++i_) {                                   \
            if (i_ < 9 || tid < 144) {                                      \
                gload_lds16(wsb + off[i_], d_ + i_ * 4096);                 \
                if (i_ < 5 || (i_ == 5 && tid < 16)) {                      \
                    if (off[i_] != zOff) off[i_] += 524288u;                \
                } else {                                                    \
                    off[i_] += 73728u;                                      \
                }                                                           \
            }                                                               \
        } } while (0)

    C4_STAGE(smem);

    for (int pp = 0; pp < NPH; ++pp) {
        __syncthreads();
        if (pp < NPH - 1) C4_STAGE(smem + ((pp + 1) & 1) * C4_BUF);
        const char* base = smem + (pp & 1) * C4_BUF;
        const char* aS = base;              // sr act
        const char* aH = base + C4_ACT;     // hr act
        __builtin_amdgcn_s_setprio(1);      // T5: favor compute wave
        #pragma unroll
        for (int g = 0; g < 2; ++g) {
            i32x8 A[4];
            #pragma unroll
            for (int mt = 0; mt < 4; ++mt) {
                const char* pa = base + awmx + g * 8192 + mt * 256;
                U2 u{*(const u32x4*)pa, *(const u32x4*)(pa + 1024)};
                A[mt] = __builtin_bit_cast(i32x8, u);
            }
            #pragma unroll
            for (int nt = 0; nt < 4; ++nt) {
                const int bo = bnt0 + nt * 288 + bmx[g];
                U2 us{*(const u32x4*)(aS + bo), *(const u32x4*)(aS + bo + 5184)};
                i32x8 BS = __builtin_bit_cast(i32x8, us);
                #pragma unroll
                for (int mt = 0; mt < 4; ++mt)
                    accS[mt][nt] = __builtin_amdgcn_mfma_scale_f32_16x16x128_f8f6f4(
                        A[mt], BS, accS[mt][nt], 0, 0,
                        0, 0x7F7F7F7F, 0, 0x7F7F7F7F);
                U2 uh{*(const u32x4*)(aH + bo), *(const u32x4*)(aH + bo + 5184)};
                i32x8 BH = __builtin_bit_cast(i32x8, uh);
                #pragma unroll
                for (int mt = 0; mt < 4; ++mt)
                    accH[mt][nt] = __builtin_amdgcn_mfma_scale_f32_16x16x128_f8f6f4(
                        A[mt], BH, accH[mt][nt], 0, 0,
                        0, 0x7F7F7F7F, 0, 0x7F7F7F7F);
            }
        }
        {
            long A8[4];
            #pragma unroll
            for (int mt = 0; mt < 4; ++mt)
                A8[mt] = *(const long*)(base + aw8 + mt * 256);
            #pragma unroll
            for (int nt = 0; nt < 4; ++nt) {
                long bs = *(const long*)(aS + ab8 + nt * 288);
                long bh = *(const long*)(aH + ab8 + nt * 288);
                #pragma unroll
                for (int mt = 0; mt < 4; ++mt) {
                    accS[mt][nt] = __builtin_amdgcn_mfma_f32_16x16x32_fp8_fp8(
                        A8[mt], bs, accS[mt][nt], 0, 0, 0);
                    accH[mt][nt] = __builtin_amdgcn_mfma_f32_16x16x32_fp8_fp8(
                        A8[mt], bh, accH[mt][nt], 0, 0, 0);
                }
            }
        }
        __builtin_amdgcn_s_setprio(0);
    }
#undef C4_STAGE

    if (EPI == 0) {
        // store both images, NC16HW16 fp8, relu
        #pragma unroll
        for (int nt = 0; nt < 4; ++nt) {
            const int y = y0 + wn * 4 + nt;
            #pragma unroll
            for (int mt = 0; mt < 4; ++mt) {
                const int cb = co0 + mt * 16 + kq * 4;
                const f32x4 bv = *(const f32x4*)(bias + cb);
                const unsigned po = (unsigned)(((cb >> 4) * 16384 +
                                    y * 128 + x0 + xl) * 16 + (cb & 15));
                float v[4];
                #pragma unroll
                for (int r = 0; r < 4; ++r) v[r] = fmaxf(accS[mt][nt][r] + bv[r], 0.f);
                int w0 = __builtin_amdgcn_cvt_pk_fp8_f32(v[0], v[1], 0, false);
                w0 = __builtin_amdgcn_cvt_pk_fp8_f32(v[2], v[3], w0, true);
                *(int*)(wsb + outOff + ((unsigned)img << 22) + po) = w0;
                #pragma unroll
                for (int r = 0; r < 4; ++r) v[r] = fmaxf(accH[mt][nt][r] + bv[r], 0.f);
                w0 = __builtin_amdgcn_cvt_pk_fp8_f32(v[0], v[1], 0, false);
                w0 = __builtin_amdgcn_cvt_pk_fp8_f32(v[2], v[3], w0, true);
                *(int*)(wsb + outOff + outHrOff + ((unsigned)img << 22) + po) = w0;
            }
        }
    } else {
        // perceptual partial: sum (relu(sr)-relu(hr))^2
        float s = 0.f;
        #pragma unroll
        for (int mt = 0; mt < 4; ++mt) {
            const int cb = co0 + mt * 16 + kq * 4;
            const f32x4 bv = *(const f32x4*)(bias + cb);
            #pragma unroll
            for (int nt = 0; nt < 4; ++nt) {
                #pragma unroll
                for (int r = 0; r < 4; ++r) {
                    float vs = fmaxf(accS[mt][nt][r] + bv[r], 0.f);
                    float vh = fmaxf(accH[mt][nt][r] + bv[r], 0.f);
                    float d = vs - vh;
                    s += d * d;
                }
            }
        }
        #pragma unroll
        for (int o = 32; o > 0; o >>= 1) s += __shfl_down(s, o, 64);
        __syncthreads();
        if (lane == 0) *(float*)(smem + wn * 4) = s;
        __syncthreads();
        if (tid == 0) {
            float tot = *(float*)(smem) + *(float*)(smem + 4) +
                        *(float*)(smem + 8) + *(float*)(smem + 12);
            atomicAdd(pacc, tot);
        }
    }
}

// ---------------------------------------------------------------------------
// launch
// ---------------------------------------------------------------------------
extern "C" void kernel_launch(void* const* d_in, const int* in_sizes, int n_in,
                              void* d_out, int out_size, void* d_ws, size_t ws_size,
                              hipStream_t stream) {
    const float* sr = (const float*)d_in[0];
    const float* hr = (const float*)d_in[1];
    const float* w1 = (const float*)d_in[2];
    const float* b1 = (const float*)d_in[3];
    const float* w2 = (const float*)d_in[4];
    const float* b2 = (const float*)d_in[5];
    const float* w3 = (const float*)d_in[6];
    const float* b3 = (const float*)d_in[7];
    const float* w4 = (const float*)d_in[8];
    const float* b4 = (const float*)d_in[9];
    float* out = (float*)d_out;

    char* ws = (char*)d_ws;
    size_t off = 0;
    float* accs = (float*)(ws + off); off += 256;
    float* zbuf = (float*)(ws + off); off += 256;
    u8* wb2 = (u8*)(ws + off); off += (size_t)128 * 9 * 64;
    u8* wb3 = (u8*)(ws + off); off += (size_t)256 * 9 * 128;
    u8* wb4 = (u8*)(ws + off); off += (size_t)256 * 9 * 256;
    const size_t fixed = (off + 255) & ~(size_t)255;

    const size_t MB = 1024u * 1024u;
    // per batch-image pair (sr+hr): A 8MB, P 4MB = 12MB
    int nb = 8;
    while (nb > 1 && fixed + (size_t)nb * 12 * MB > ws_size) nb >>= 1;

    u8* A = (u8*)(ws + fixed);                          // fp8 planar (conv1 out / conv3 out)
    u8* P = (u8*)(ws + fixed + (size_t)nb * 8 * MB);    // fp8 planar pooled

    const unsigned zOffU = (unsigned)((char*)zbuf - ws);
    const unsigned aOffU = (unsigned)fixed;
    const unsigned pOffU = (unsigned)(fixed + (size_t)nb * 8 * MB);

    const int c1n = (nb == 8) ? 4096 : 0;   // conv1 folded into prep (fast path)

    hipMemsetAsync(ws, 0, 512, stream);                 // accs + zbuf
    prep_loss_kernel<<<6216 + c1n, 256, 0, stream>>>(
        w2, wb2, w3, wb3, w4, wb4, sr, hr, accs, w1, b1, A);

    for (int b0 = 0; b0 < 8; b0 += nb) {
        const int ni = 2 * nb;   // sr images then hr images
        // conv1 (sr+hr merged) -> A (NC8HW8); folded into prep when nb==8
        if (c1n == 0)
            conv1_kernel<<<dim3(256, ni), 256, 0, stream>>>(sr, hr, nb, b0, w1, b1, A);
        // conv2 + fused pool, single-stage (merged) -> P  (NC16HW16)
        conv2_ss<<<dim3(16, 16, ni * 2), 256, 0, stream>>>(A, wb2, b2, P, zbuf);
        // conv3 fused: sr+hr per phase, shared A-frags -> A (NC16HW16 both)
        conv34_fused<4, 0, 21><<<dim3(8, 8, nb * 4), 256, 0, stream>>>(
            ws, pOffU, (unsigned)((char*)wb3 - ws), zOffU, b3,
            (unsigned)nb << 21, aOffU, (unsigned)nb << 22, nullptr);
        // conv4 fused: sr+hr per phase, fused perceptual
        conv34_fused<8, 1, 22><<<dim3(8, 8, nb * 4), 256, 0, stream>>>(
            ws, aOffU, (unsigned)((char*)wb4 - ws), zOffU, b4,
            (unsigned)nb << 22, 0u, 0u, accs + 2);
    }

    finalize_kernel<<<1, 1, 0, stream>>>(accs, out);
}

// Round 5
// 384.093 us; speedup vs baseline: 1.0213x; 1.0213x over previous
//
#include <hip/hip_runtime.h>
#include <hip/hip_bf16.h>

typedef __hip_bfloat16 bf16;
typedef unsigned char u8;
typedef __attribute__((ext_vector_type(4))) float f32x4;
typedef __attribute__((ext_vector_type(8))) int i32x8;
typedef __attribute__((ext_vector_type(4))) unsigned int u32x4;

struct L4 { long a, b, c, d; };
struct U2 { u32x4 x, y; };

// async global->LDS 16B copy; LDS dst must be wave-uniform base + lane*16
typedef __attribute__((address_space(3))) unsigned int lds_uint;
typedef __attribute__((address_space(1))) const unsigned int g_uint;
__device__ inline void gload_lds16(const void* g, void* l) {
    __builtin_amdgcn_global_load_lds((g_uint*)g, (lds_uint*)l, 16, 0, 0);
}

__device__ inline void block_reduce_atomic(float v, float* dst) {
    #pragma unroll
    for (int o = 32; o > 0; o >>= 1) v += __shfl_down(v, o, 64);
    __shared__ float ws[8];
    const int lane = threadIdx.x & 63;
    const int wid  = threadIdx.x >> 6;
    if (lane == 0) ws[wid] = v;
    __syncthreads();
    if (threadIdx.x == 0) {
        float s = 0.f;
        const int nw = (blockDim.x + 63) >> 6;
        for (int i = 0; i < nw; ++i) s += ws[i];
        atomicAdd(dst, s);
    }
}

// ---------------------------------------------------------------------------
// prep+loss+conv1 merged (accs/zbuf zeroed by hipMemsetAsync before this).
// blocks [0,3744): weight repack to MX layout; [3744,6216): ssim + mse;
// [6216,6216+c1n): conv1 for all 16 images (nb==8 fast path).
// wt layout per 32ch phase p: [t0..7][q(16ch)][CO][16B] then tap8 [q][CO][16B]
// ---------------------------------------------------------------------------
__global__ void prep_loss_kernel(
    const float* __restrict__ w2, u8* __restrict__ wb2,
    const float* __restrict__ w3, u8* __restrict__ wb3,
    const float* __restrict__ w4, u8* __restrict__ wb4,
    const float* __restrict__ x, const float* __restrict__ y,
    float* __restrict__ accs,
    const float* __restrict__ w1, const float* __restrict__ b1,
    u8* __restrict__ aout) {
    const int blk = blockIdx.x;
    if (blk >= 6216) {
        // conv1: CIN=1, CO=64, fp32 NCHW -> fp8 planar NC8HW8, relu. 16 imgs.
        const int lb2 = blk - 6216;
        const int img = lb2 >> 8;
        const float* in = (img < 8) ? (x + (size_t)img * 65536)
                                    : (y + (size_t)(img - 8) * 65536);
        const int px = ((lb2 & 255) << 8) + threadIdx.x;
        const int yy = px >> 8, xx = px & 255;
        float p[9];
        #pragma unroll
        for (int dy = 0; dy < 3; ++dy)
            #pragma unroll
            for (int dx = 0; dx < 3; ++dx) {
                int gy = yy + dy - 1, gx = xx + dx - 1;
                float v = 0.f;
                if ((unsigned)gy < 256u && (unsigned)gx < 256u)
                    v = in[(size_t)gy * 256 + gx];
                p[dy * 3 + dx] = v;
            }
        #pragma unroll
        for (int g = 0; g < 8; ++g) {
            float v[8];
            #pragma unroll
            for (int c = 0; c < 8; ++c) {
                int co = g * 8 + c;
                float a = b1[co];
                #pragma unroll
                for (int k = 0; k < 9; ++k) a += w1[co * 9 + k] * p[k];
                v[c] = fmaxf(a, 0.f);
            }
            uint2 o;
            int r;
            r = __builtin_amdgcn_cvt_pk_fp8_f32(v[0], v[1], 0, false);
            o.x = __builtin_amdgcn_cvt_pk_fp8_f32(v[2], v[3], r, true);
            r = __builtin_amdgcn_cvt_pk_fp8_f32(v[4], v[5], 0, false);
            o.y = __builtin_amdgcn_cvt_pk_fp8_f32(v[6], v[7], r, true);
            *(uint2*)(aout + (((size_t)img * 8 + g) * 65536 + px) * 8) = o;
        }
        return;
    }
    if (blk < 3744) {
        const float* w; u8* wb; int CIN, CO, idx;
        if (blk < 288)       { w = w2; wb = wb2; CIN = 64;  CO = 128; idx = blk * 256 + threadIdx.x; }
        else if (blk < 1440) { w = w3; wb = wb3; CIN = 128; CO = 256; idx = (blk - 288) * 256 + threadIdx.x; }
        else                 { w = w4; wb = wb4; CIN = 256; CO = 256; idx = (blk - 1440) * 256 + threadIdx.x; }
        int n = CO * 9 * CIN;
        if (idx >= n) return;
        int t = idx % 9;
        int rest = idx / 9;
        int ci = rest % CIN;
        int co = rest / CIN;
        float v = w[idx];            // w flat = ((co*CIN+ci)*9 + t)
        int p = ci >> 5, c32 = ci & 31;
        size_t off = (size_t)p * 288 * CO;
        if (t < 8) off += (((size_t)t * 2 + (c32 >> 4)) * CO + co) * 16 + (c32 & 15);
        else       off += 256 * (size_t)CO + (((size_t)(c32 >> 4)) * CO + co) * 16 + (c32 & 15);
        int r = __builtin_amdgcn_cvt_pk_fp8_f32(v, v, 0, false);
        wb[off] = (u8)(r & 0xff);
        return;
    }
    const int lb = blk - 3744;
    float val = 0.f;
    float* dst;
    if (lb < 1960) {
        dst = accs + 1;
        const int b = lb / 245;
        const int t = (lb - b * 245) * 256 + threadIdx.x;
        if (t < 250 * 250) {
            const int i = t / 250, j = t - (t / 250) * 250;
            const float* xp = x + (size_t)b * 65536;
            const float* yp = y + (size_t)b * 65536;
            float sx = 0.f, sy = 0.f, sxx = 0.f, syy = 0.f, sxy = 0.f;
            #pragma unroll
            for (int dy = 0; dy < 7; ++dy) {
                const float* xr = xp + (size_t)(i + dy) * 256 + j;
                const float* yr = yp + (size_t)(i + dy) * 256 + j;
                #pragma unroll
                for (int dx = 0; dx < 7; ++dx) {
                    float a = xr[dx], c = yr[dx];
                    sx += a; sy += c;
                    sxx += a * a; syy += c * c; sxy += a * c;
                }
            }
            const float inv = 1.f / 49.f;
            const float cn  = 49.f / 48.f;
            float ux = sx * inv, uy = sy * inv;
            float vx  = cn * (sxx * inv - ux * ux);
            float vy  = cn * (syy * inv - uy * uy);
            float vxy = cn * (sxy * inv - ux * uy);
            const float C1 = 1e-4f, C2 = 9e-4f;
            val = ((2.f * ux * uy + C1) * (2.f * vxy + C2)) /
                  ((ux * ux + uy * uy + C1) * (vx + vy + C2));
        }
    } else {
        dst = accs + 0;
        int i = (lb - 1960) * 256 + threadIdx.x;   // < 131072 float4s
        float4 a = ((const float4*)x)[i];
        float4 b = ((const float4*)y)[i];
        float d0 = a.x - b.x, d1 = a.y - b.y, d2 = a.z - b.z, d3 = a.w - b.w;
        val = d0 * d0 + d1 * d1 + d2 * d2 + d3 * d3;
    }
    block_reduce_atomic(val, dst);
}

__global__ void finalize_kernel(const float* __restrict__ accs, float* __restrict__ out) {
    if (threadIdx.x == 0) {
        float mse    = accs[0] * (1.f / 524288.f);
        float ssim_l = 1.f - accs[1] * (1.f / 500000.f);
        float perc   = accs[2] * (1.f / 33554432.f);
        out[0] = mse + 0.5f * ssim_l + 0.1f * perc;
        out[1] = mse;
        out[2] = ssim_l;
        out[3] = perc;
    }
}

// ---------------------------------------------------------------------------
// conv1 standalone (fallback for nb<8 workspace-constrained path).
// ---------------------------------------------------------------------------
__global__ __launch_bounds__(256) void conv1_kernel(
    const float* __restrict__ sr, const float* __restrict__ hr, int nb, int b0,
    const float* __restrict__ w, const float* __restrict__ bias,
    u8* __restrict__ out) {
    const int H = 256, W = 256;
    const int img = blockIdx.y;
    const float* in = (img < nb) ? (sr + (size_t)(b0 + img) * 65536)
                                 : (hr + (size_t)(b0 + img - nb) * 65536);
    int px = blockIdx.x * 256 + threadIdx.x;
    int y = px >> 8, x = px & 255;
    float p[9];
    #pragma unroll
    for (int dy = 0; dy < 3; ++dy)
        #pragma unroll
        for (int dx = 0; dx < 3; ++dx) {
            int gy = y + dy - 1, gx = x + dx - 1;
            float v = 0.f;
            if ((unsigned)gy < (unsigned)H && (unsigned)gx < (unsigned)W)
                v = in[(size_t)gy * W + gx];
            p[dy * 3 + dx] = v;
        }
    #pragma unroll
    for (int g = 0; g < 8; ++g) {
        float v[8];
        #pragma unroll
        for (int c = 0; c < 8; ++c) {
            int co = g * 8 + c;
            float a = bias[co];
            #pragma unroll
            for (int k = 0; k < 9; ++k) a += w[co * 9 + k] * p[k];
            v[c] = fmaxf(a, 0.f);
        }
        uint2 o;
        int r;
        r = __builtin_amdgcn_cvt_pk_fp8_f32(v[0], v[1], 0, false);
        o.x = __builtin_amdgcn_cvt_pk_fp8_f32(v[2], v[3], r, true);
        r = __builtin_amdgcn_cvt_pk_fp8_f32(v[4], v[5], 0, false);
        o.y = __builtin_amdgcn_cvt_pk_fp8_f32(v[6], v[7], r, true);
        *(uint2*)(out + (((size_t)img * 8 + g) * 65536 + px) * 8) = o;
    }
}

#define BUF_SZ   32768
#define N_ACT_CH 720
#define N_CHUNK  1872
#define WT_BOFF  11520     // 720*16

// ---------------------------------------------------------------------------
// conv2 SINGLE-STAGE: CIN=64, CO=128, H=W=256, fused 2x2 maxpool.
// Entire working set staged ONCE via 15 gload slots; ONE barrier; both 32-ch
// phases computed back-to-back with zero further syncs. 2 blocks/CU.
// Epilogue emits NC16HW16 (conv34_fused input layout).
// ---------------------------------------------------------------------------
__global__ __launch_bounds__(256, 2) void conv2_ss(
    const u8* __restrict__ in, const u8* __restrict__ wb,
    const float* __restrict__ bias, u8* __restrict__ out,
    const float* __restrict__ zbuf) {
    const int H = 256, W = 256, CO = 128;
    const size_t HW = 65536;
    const int tid  = threadIdx.x;
    const int lane = tid & 63;
    const int wn   = tid >> 6;
    const int xl = lane & 15;
    const int kq = lane >> 4;
    const int x0 = blockIdx.x * 16;
    const int y0 = blockIdx.y * 16;
    const int img = blockIdx.z >> 1;
    const int co0 = (blockIdx.z & 1) << 6;

    __shared__ __align__(16) char smem[59904];

    f32x4 acc[4][4];
    #pragma unroll
    for (int m = 0; m < 4; ++m)
        #pragma unroll
        for (int n = 0; n < 4; ++n) acc[m][n] = (f32x4){0.f, 0.f, 0.f, 0.f};

    const u8* inp = in + (size_t)img * 8 * HW * 8;   // 8 planes

    // ---- stage all 3744 chunks once (15 slots; slot14 partial tid<160) ----
    {
        char* d = smem + tid * 16;
        #pragma unroll
        for (int i = 0; i < 15; ++i) {
            int c = tid + i * 256;
            if (c >= 2 * N_CHUNK) break;
            int ph = (c >= N_CHUNK) ? 1 : 0;
            int c2 = c - ph * N_CHUNK;
            const char* src = (const char*)zbuf;
            if (c2 < N_ACT_CH) {
                int g = c2 / 180, r = c2 - g * 180;
                int row = r / 10, pp = r - row * 10;
                int gy = y0 - 1 + row, colb = x0 - 2 + pp * 2;
                if ((unsigned)gy < (unsigned)H && (unsigned)colb < (unsigned)(W - 1))
                    src = (const char*)(inp + (((size_t)(g + ph * 4)) * HW +
                                              (size_t)gy * W + colb) * 8);
            } else {
                int c3 = c2 - N_ACT_CH;
                size_t o;
                if (c3 < 1024) {
                    int gt = c3 >> 6, co = c3 & 63;
                    o = ((size_t)gt * CO + co0 + co) * 16;
                } else {
                    int c4 = c3 - 1024;
                    int q = c4 >> 6, co = c4 & 63;
                    o = 256 * (size_t)CO + ((size_t)q * CO + co0 + co) * 16;
                }
                src = (const char*)(wb + (size_t)ph * 288 * CO + o);
            }
            gload_lds16(src, d + i * 4096);
        }
    }

    int mxo[2];
    #pragma unroll
    for (int g = 0; g < 2; ++g) {
        int t = g * 4 + kq;
        int dy = t / 3, dx = t - dy * 3;
        mxo[g] = (dy * 20 + dx) * 8;
    }
    const int abase = ((wn * 4) * 20 + xl + 1) * 8;
    const int awmx  = WT_BOFF + kq * 2048 + xl * 16;
    const int aw8   = WT_BOFF + 16384 + (kq >> 1) * 1024 + xl * 16 + (kq & 1) * 8;
    const int ab8   = kq * 2880 + abase + (2 * 20 + 2) * 8;

    __syncthreads();   // single drain

    #pragma unroll
    for (int p = 0; p < 2; ++p) {
        const char* base = smem + p * 29952;
        #pragma unroll
        for (int g = 0; g < 2; ++g) {
            i32x8 A[4];
            #pragma unroll
            for (int mt = 0; mt < 4; ++mt) {
                const char* pa = base + awmx + g * 8192 + mt * 256;
                U2 u{*(const u32x4*)pa, *(const u32x4*)(pa + 1024)};
                A[mt] = __builtin_bit_cast(i32x8, u);
            }
            #pragma unroll
            for (int nt = 0; nt < 4; ++nt) {
                const char* pb = base + abase + mxo[g] + nt * 160;
                L4 l{*(const long*)pb, *(const long*)(pb + 2880),
                     *(const long*)(pb + 5760), *(const long*)(pb + 8640)};
                i32x8 B = __builtin_bit_cast(i32x8, l);
                #pragma unroll
                for (int mt = 0; mt < 4; ++mt)
                    acc[mt][nt] = __builtin_amdgcn_mfma_scale_f32_16x16x128_f8f6f4(
                        A[mt], B, acc[mt][nt], 0, 0,
                        0, 0x7F7F7F7F, 0, 0x7F7F7F7F);
            }
        }
        {
            long A8[4], B8[4];
            #pragma unroll
            for (int mt = 0; mt < 4; ++mt)
                A8[mt] = *(const long*)(base + aw8 + mt * 256);
            #pragma unroll
            for (int nt = 0; nt < 4; ++nt)
                B8[nt] = *(const long*)(base + ab8 + nt * 160);
            #pragma unroll
            for (int mt = 0; mt < 4; ++mt)
                #pragma unroll
                for (int nt = 0; nt < 4; ++nt)
                    acc[mt][nt] = __builtin_amdgcn_mfma_f32_16x16x32_fp8_fp8(
                        A8[mt], B8[nt], acc[mt][nt], 0, 0, 0);
        }
    }

    // pool epilogue (C/D: col=xl; row(co in 16) = kq*4+reg) -> NC16HW16
    const int Hp = H >> 1, Wp = W >> 1;
    const size_t HWp = (size_t)Hp * Wp;
    #pragma unroll
    for (int j = 0; j < 2; ++j) {
        const int py = (y0 + wn * 4 + 2 * j) >> 1;
        const int px = (x0 + xl) >> 1;
        #pragma unroll
        for (int mt = 0; mt < 4; ++mt) {
            const int cb = co0 + mt * 16 + kq * 4;
            const f32x4 bv = *(const f32x4*)(bias + cb);
            float v[4];
            #pragma unroll
            for (int r = 0; r < 4; ++r) {
                float a = acc[mt][2 * j][r] + bv[r];
                float b = acc[mt][2 * j + 1][r] + bv[r];
                float m = fmaxf(a, b);
                m = fmaxf(m, __shfl_xor(m, 1));   // fold x pair
                v[r] = fmaxf(m, 0.f);
            }
            if (!(lane & 1)) {
                int w0 = __builtin_amdgcn_cvt_pk_fp8_f32(v[0], v[1], 0, false);
                w0 = __builtin_amdgcn_cvt_pk_fp8_f32(v[2], v[3], w0, true);
                *(int*)(out + (((size_t)img * (CO >> 4) + (cb >> 4)) * HWp +
                               (size_t)py * Wp + px) * 16 + (cb & 15)) = w0;
            }
        }
    }
}

// ---------------------------------------------------------------------------
// conv34_fused: sr+hr computed TOGETHER each 32-ch phase, shared A-fragments.
// u32 workspace-relative offsets (R2-proven, no spill). NPH = CIN/32 phases.
// EPI: 0 = store both imgs NC16HW16 (conv3), 1 = perceptual reduce (conv4).
// R5: all LDS reads of a group HOISTED before its MFMA cluster (A[4]+BS[4]+
// BH[4] in regs, then 32 MFMAs with no loads interleaved) -- collapses the
// per-wave load->wait->mfma serial chain; compiler emits decrementing
// lgkmcnt(N). R4 skew reverted (null: stall is intra-wave, not phase-lock).
// ---------------------------------------------------------------------------
#define C4_ACT  10368      // one image's act bytes per phase (2*18*18*16)
#define C4_WT   20736      // weight region offset (2*C4_ACT)
#define C4_BUF  39168      // per-phase buffer (C4_WT + 18432)
#define C4_NCH  2448       // chunks per phase (1296 act + 1152 wt)

template <int NPH, int EPI, int IMGSH>
__global__ __launch_bounds__(256, 2) void conv34_fused(
    char* __restrict__ wsb,          // workspace base
    unsigned inOff,                  // input base offset in ws (NC16HW16 fp8)
    unsigned wOff,                   // packed weight offset in ws
    unsigned zOff,                   // zbuf offset in ws
    const float* __restrict__ bias,
    unsigned inHrOff,                // hr image region offset from sr region
    unsigned outOff,                 // EPI0: output base offset in ws
    unsigned outHrOff,               // EPI0: hr output region offset
    float* __restrict__ pacc) {      // EPI1: perceptual accumulator
    const int tid  = threadIdx.x;
    const int lane = tid & 63;
    const int wn   = tid >> 6;
    const int xl = lane & 15;
    const int kq = lane >> 4;
    const int x0 = blockIdx.x * 16;
    const int y0 = blockIdx.y * 16;
    const int img = blockIdx.z >> 2;
    const int co0 = (blockIdx.z & 3) << 6;

    __shared__ __align__(16) char smem[2 * C4_BUF];   // 78336 B

    f32x4 accS[4][4], accH[4][4];
    #pragma unroll
    for (int m = 0; m < 4; ++m)
        #pragma unroll
        for (int n = 0; n < 4; ++n) {
            accS[m][n] = (f32x4){0.f, 0.f, 0.f, 0.f};
            accH[m][n] = (f32x4){0.f, 0.f, 0.f, 0.f};
        }

    const unsigned inoff = inOff + ((unsigned)img << IMGSH);

    // chunk map: [0,648) sr act, [648,1296) hr act, [1296,2448) weights
    //   act: c2 = g2*324 + row*18 + col  (18x18 exact halo, 16-ch chunks)
    //   wt : c3 < 1024 -> [kblk(16)][co(64)]; else tap8 [h(2)][co(64)]
    unsigned off[10];
    #pragma unroll
    for (int i = 0; i < 10; ++i) {
        int c = tid + i * 256;
        off[i] = zOff;                         // zero-halo sentinel
        if (c < 1296) {
            int c2 = (c >= 648) ? c - 648 : c;
            int g2 = c2 / 324, rem = c2 - g2 * 324;
            int row = rem / 18, col = rem - row * 18;
            int gy = y0 - 1 + row, gx = x0 - 1 + col;
            if ((unsigned)gy < 128u && (unsigned)gx < 128u)
                off[i] = inoff + ((c >= 648) ? inHrOff : 0u) +
                         (unsigned)((g2 * 16384 + gy * 128 + gx) * 16);
        } else if (c < C4_NCH) {
            int c3 = c - 1296;
            unsigned o;
            if (c3 < 1024) {
                int kblk = c3 >> 6, co = c3 & 63;
                o = (unsigned)((kblk * 256 + co0 + co) * 16);
            } else {
                int c4 = c3 - 1024;
                int h = c4 >> 6, co = c4 & 63;
                o = 65536u + (unsigned)((h * 256 + co0 + co) * 16);
            }
            off[i] = wOff + o;
        }
    }

    // B addressing: halo row r = wn*4+nt+dy, col = xl+dx; 16-ch chunk = 16B,
    // row stride 288, g2 (16-ch half) stride 5184 -> 2 x b128 per frag.
    int bmx[2];
    #pragma unroll
    for (int g = 0; g < 2; ++g) {
        int t = g * 4 + kq;
        int dy = t / 3, dx = t - dy * 3;
        bmx[g] = (dy * 18 + dx) * 16;
    }
    const int bnt0 = ((wn * 4) * 18 + xl) * 16;   // + nt*288
    const int awmx = C4_WT + kq * 2048 + xl * 16;
    const int aw8  = C4_WT + 16384 + (kq >> 1) * 1024 + xl * 16 + (kq & 1) * 8;
    const int ab8  = ((wn * 4 + 2) * 18 + xl + 2) * 16 +
                     (kq >> 1) * 5184 + (kq & 1) * 8;     // + nt*288

    // advance per phase: act +524288 (2 planes) unless sentinel; wt +73728
#define C4_STAGE(DB) do {                                                   \
        char* d_ = (DB) + tid * 16;                                         \
        _Pragma("unroll")                                                   \
        for (int i_ = 0; i_ < 10; ++i_) {                                   \
            if (i_ < 9 || tid < 144) {                                      \
                gload_lds16(wsb + off[i_], d_ + i_ * 4096);                 \
                if (i_ < 5 || (i_ == 5 && tid < 16)) {                      \
                    if (off[i_] != zOff) off[i_] += 524288u;                \
                } else {                                                    \
                    off[i_] += 73728u;                                      \
                }                                                           \
            }                                                               \
        } } while (0)

    C4_STAGE(smem);

    for (int pp = 0; pp < NPH; ++pp) {
        __syncthreads();
        if (pp < NPH - 1) C4_STAGE(smem + ((pp + 1) & 1) * C4_BUF);
        const char* base = smem + (pp & 1) * C4_BUF;
        const char* aS = base;              // sr act
        const char* aH = base + C4_ACT;     // hr act
        __builtin_amdgcn_s_setprio(1);      // T5: favor compute wave
        #pragma unroll
        for (int g = 0; g < 2; ++g) {
            // ---- hoist ALL loads of this group before its MFMA cluster ----
            i32x8 A[4];
            #pragma unroll
            for (int mt = 0; mt < 4; ++mt) {
                const char* pa = base + awmx + g * 8192 + mt * 256;
                U2 u{*(const u32x4*)pa, *(const u32x4*)(pa + 1024)};
                A[mt] = __builtin_bit_cast(i32x8, u);
            }
            i32x8 BS[4], BH[4];
            #pragma unroll
            for (int nt = 0; nt < 4; ++nt) {
                const int bo = bnt0 + nt * 288 + bmx[g];
                U2 us{*(const u32x4*)(aS + bo), *(const u32x4*)(aS + bo + 5184)};
                BS[nt] = __builtin_bit_cast(i32x8, us);
                U2 uh{*(const u32x4*)(aH + bo), *(const u32x4*)(aH + bo + 5184)};
                BH[nt] = __builtin_bit_cast(i32x8, uh);
            }
            // ---- 32 MFMAs, no loads interleaved ----
            #pragma unroll
            for (int nt = 0; nt < 4; ++nt) {
                #pragma unroll
                for (int mt = 0; mt < 4; ++mt)
                    accS[mt][nt] = __builtin_amdgcn_mfma_scale_f32_16x16x128_f8f6f4(
                        A[mt], BS[nt], accS[mt][nt], 0, 0,
                        0, 0x7F7F7F7F, 0, 0x7F7F7F7F);
                #pragma unroll
                for (int mt = 0; mt < 4; ++mt)
                    accH[mt][nt] = __builtin_amdgcn_mfma_scale_f32_16x16x128_f8f6f4(
                        A[mt], BH[nt], accH[mt][nt], 0, 0,
                        0, 0x7F7F7F7F, 0, 0x7F7F7F7F);
            }
        }
        {
            long A8[4], BS8[4], BH8[4];
            #pragma unroll
            for (int mt = 0; mt < 4; ++mt)
                A8[mt] = *(const long*)(base + aw8 + mt * 256);
            #pragma unroll
            for (int nt = 0; nt < 4; ++nt) {
                BS8[nt] = *(const long*)(aS + ab8 + nt * 288);
                BH8[nt] = *(const long*)(aH + ab8 + nt * 288);
            }
            #pragma unroll
            for (int nt = 0; nt < 4; ++nt) {
                #pragma unroll
                for (int mt = 0; mt < 4; ++mt) {
                    accS[mt][nt] = __builtin_amdgcn_mfma_f32_16x16x32_fp8_fp8(
                        A8[mt], BS8[nt], accS[mt][nt], 0, 0, 0);
                    accH[mt][nt] = __builtin_amdgcn_mfma_f32_16x16x32_fp8_fp8(
                        A8[mt], BH8[nt], accH[mt][nt], 0, 0, 0);
                }
            }
        }
        __builtin_amdgcn_s_setprio(0);
    }
#undef C4_STAGE

    if (EPI == 0) {
        // store both images, NC16HW16 fp8, relu
        #pragma unroll
        for (int nt = 0; nt < 4; ++nt) {
            const int y = y0 + wn * 4 + nt;
            #pragma unroll
            for (int mt = 0; mt < 4; ++mt) {
                const int cb = co0 + mt * 16 + kq * 4;
                const f32x4 bv = *(const f32x4*)(bias + cb);
                const unsigned po = (unsigned)(((cb >> 4) * 16384 +
                                    y * 128 + x0 + xl) * 16 + (cb & 15));
                float v[4];
                #pragma unroll
                for (int r = 0; r < 4; ++r) v[r] = fmaxf(accS[mt][nt][r] + bv[r], 0.f);
                int w0 = __builtin_amdgcn_cvt_pk_fp8_f32(v[0], v[1], 0, false);
                w0 = __builtin_amdgcn_cvt_pk_fp8_f32(v[2], v[3], w0, true);
                *(int*)(wsb + outOff + ((unsigned)img << 22) + po) = w0;
                #pragma unroll
                for (int r = 0; r < 4; ++r) v[r] = fmaxf(accH[mt][nt][r] + bv[r], 0.f);
                w0 = __builtin_amdgcn_cvt_pk_fp8_f32(v[0], v[1], 0, false);
                w0 = __builtin_amdgcn_cvt_pk_fp8_f32(v[2], v[3], w0, true);
                *(int*)(wsb + outOff + outHrOff + ((unsigned)img << 22) + po) = w0;
            }
        }
    } else {
        // perceptual partial: sum (relu(sr)-relu(hr))^2
        float s = 0.f;
        #pragma unroll
        for (int mt = 0; mt < 4; ++mt) {
            const int cb = co0 + mt * 16 + kq * 4;
            const f32x4 bv = *(const f32x4*)(bias + cb);
            #pragma unroll
            for (int nt = 0; nt < 4; ++nt) {
                #pragma unroll
                for (int r = 0; r < 4; ++r) {
                    float vs = fmaxf(accS[mt][nt][r] + bv[r], 0.f);
                    float vh = fmaxf(accH[mt][nt][r] + bv[r], 0.f);
                    float d = vs - vh;
                    s += d * d;
                }
            }
        }
        #pragma unroll
        for (int o = 32; o > 0; o >>= 1) s += __shfl_down(s, o, 64);
        __syncthreads();
        if (lane == 0) *(float*)(smem + wn * 4) = s;
        __syncthreads();
        if (tid == 0) {
            float tot = *(float*)(smem) + *(float*)(smem + 4) +
                        *(float*)(smem + 8) + *(float*)(smem + 12);
            atomicAdd(pacc, tot);
        }
    }
}

// ---------------------------------------------------------------------------
// launch
// ---------------------------------------------------------------------------
extern "C" void kernel_launch(void* const* d_in, const int* in_sizes, int n_in,
                              void* d_out, int out_size, void* d_ws, size_t ws_size,
                              hipStream_t stream) {
    const float* sr = (const float*)d_in[0];
    const float* hr = (const float*)d_in[1];
    const float* w1 = (const float*)d_in[2];
    const float* b1 = (const float*)d_in[3];
    const float* w2 = (const float*)d_in[4];
    const float* b2 = (const float*)d_in[5];
    const float* w3 = (const float*)d_in[6];
    const float* b3 = (const float*)d_in[7];
    const float* w4 = (const float*)d_in[8];
    const float* b4 = (const float*)d_in[9];
    float* out = (float*)d_out;

    char* ws = (char*)d_ws;
    size_t off = 0;
    float* accs = (float*)(ws + off); off += 256;
    float* zbuf = (float*)(ws + off); off += 256;
    u8* wb2 = (u8*)(ws + off); off += (size_t)128 * 9 * 64;
    u8* wb3 = (u8*)(ws + off); off += (size_t)256 * 9 * 128;
    u8* wb4 = (u8*)(ws + off); off += (size_t)256 * 9 * 256;
    const size_t fixed = (off + 255) & ~(size_t)255;

    const size_t MB = 1024u * 1024u;
    // per batch-image pair (sr+hr): A 8MB, P 4MB = 12MB
    int nb = 8;
    while (nb > 1 && fixed + (size_t)nb * 12 * MB > ws_size) nb >>= 1;

    u8* A = (u8*)(ws + fixed);                          // fp8 planar (conv1 out / conv3 out)
    u8* P = (u8*)(ws + fixed + (size_t)nb * 8 * MB);    // fp8 planar pooled

    const unsigned zOffU = (unsigned)((char*)zbuf - ws);
    const unsigned aOffU = (unsigned)fixed;
    const unsigned pOffU = (unsigned)(fixed + (size_t)nb * 8 * MB);

    const int c1n = (nb == 8) ? 4096 : 0;   // conv1 folded into prep (fast path)

    hipMemsetAsync(ws, 0, 512, stream);                 // accs + zbuf
    prep_loss_kernel<<<6216 + c1n, 256, 0, stream>>>(
        w2, wb2, w3, wb3, w4, wb4, sr, hr, accs, w1, b1, A);

    for (int b0 = 0; b0 < 8; b0 += nb) {
        const int ni = 2 * nb;   // sr images then hr images
        // conv1 (sr+hr merged) -> A (NC8HW8); folded into prep when nb==8
        if (c1n == 0)
            conv1_kernel<<<dim3(256, ni), 256, 0, stream>>>(sr, hr, nb, b0, w1, b1, A);
        // conv2 + fused pool, single-stage (merged) -> P  (NC16HW16)
        conv2_ss<<<dim3(16, 16, ni * 2), 256, 0, stream>>>(A, wb2, b2, P, zbuf);
        // conv3 fused: sr+hr per phase, shared A-frags -> A (NC16HW16 both)
        conv34_fused<4, 0, 21><<<dim3(8, 8, nb * 4), 256, 0, stream>>>(
            ws, pOffU, (unsigned)((char*)wb3 - ws), zOffU, b3,
            (unsigned)nb << 21, aOffU, (unsigned)nb << 22, nullptr);
        // conv4 fused: sr+hr per phase, fused perceptual
        conv34_fused<8, 1, 22><<<dim3(8, 8, nb * 4), 256, 0, stream>>>(
            ws, aOffU, (unsigned)((char*)wb4 - ws), zOffU, b4,
            (unsigned)nb << 22, 0u, 0u, accs + 2);
    }

    finalize_kernel<<<1, 1, 0, stream>>>(accs, out);
}